// Round 2
// baseline (9583.075 us; speedup 1.0000x reference)
//
#include <hip/hip_runtime.h>
#include <math.h>

static __device__ __forceinline__ float sigf(float x){
  return 1.0f / (1.0f + __expf(-x));
}
static __device__ __forceinline__ float tanhf_fast(float x){
  float ax = fabsf(x);
  float e  = __expf(-2.0f * ax);
  float t  = (1.0f - e) / (1.0f + e);
  return copysignf(t, x);
}
// sum across a quad of lanes (lanes 4k..4k+3), result in all 4 lanes
static __device__ __forceinline__ float qsum(float v){
  v += __int_as_float(__builtin_amdgcn_mov_dpp(__float_as_int(v), 0xB1, 0xF, 0xF, true)); // xor1
  v += __int_as_float(__builtin_amdgcn_mov_dpp(__float_as_int(v), 0x4E, 0xF, 0xF, true)); // xor2
  return v;
}

// ---------------------------------------------------------------------------
// L1: I=1, H=100, 512 steps, 2048 chains (1024 fwd + 1024 bwd), 4 chains/blk.
// 640 thr: t<600 compute (quad p=t>>2 owns rows 2p,2p+1; lane c=t&3 owns cols
// c*25..+25; 50 weights in VGPR). DPP quad reduction -> G[300][4].
// Phase2 (t<100): gates. x1 layout: ((cs*256+blk)*100+j)*4+cc (coalesced both sides).
// ---------------------------------------------------------------------------
__global__ __launch_bounds__(640, 5)
void gru_l1(const float* __restrict__ data,
            const float* __restrict__ wih_f, const float* __restrict__ whh_f,
            const float* __restrict__ bih_f, const float* __restrict__ bhh_f,
            const float* __restrict__ wih_b, const float* __restrict__ whh_b,
            const float* __restrict__ bih_b, const float* __restrict__ bhh_b,
            float* __restrict__ x1f, float* __restrict__ x1b,
            float* __restrict__ out)
{
  const int dir = (int)(blockIdx.x >> 8);
  const int blk = (int)(blockIdx.x & 255);
  const int t   = (int)threadIdx.x;
  const float* __restrict__ wih = dir ? wih_b : wih_f;
  const float* __restrict__ whh = dir ? whh_b : whh_f;
  const float* __restrict__ bih = dir ? bih_b : bih_f;
  const float* __restrict__ bhh = dir ? bhh_b : bhh_f;
  float* __restrict__ x1 = dir ? x1b : x1f;
  const int obase = dir ? 200 : 0;
  const int b0 = blk * 4;

  __shared__ __align__(16) float xs[4][512];
  __shared__ __align__(16) float hT[100][4];
  __shared__ __align__(16) float G[300][4];

  for (int k = t; k < 2048; k += 640){
    const int cc = k >> 9, s = k & 511;
    xs[cc][s] = data[(size_t)(b0 + cc) * 512 + (size_t)(dir ? (511 - s) : s)];
  }
  if (t < 100) *(float4*)&hT[t][0] = make_float4(0.f,0.f,0.f,0.f);

  const int p = t >> 2, c = t & 3;
  const int r0 = 2*p, r1 = 2*p + 1;
  float w[50];
  if (t < 600){
    #pragma unroll
    for (int j = 0; j < 25; ++j){
      w[j]    = whh[r0*100 + c*25 + j];
      w[25+j] = whh[r1*100 + c*25 + j];
    }
  }
  float wr=0,wz=0,wn=0,br=0,bz=0,bn=0,cr=0,cz=0,cn=0;
  if (t < 100){
    wr=wih[t]; wz=wih[t+100]; wn=wih[t+200];
    br=bih[t]; bz=bih[t+100]; bn=bih[t+200];
    cr=bhh[t]; cz=bhh[t+100]; cn=bhh[t+200];
  }
  __syncthreads();

  #pragma unroll 1
  for (int s = 0; s < 512; ++s){
    if (t < 600){
      float a00=0,a01=0,a02=0,a03=0,a10=0,a11=0,a12=0,a13=0;
      #pragma unroll
      for (int j = 0; j < 25; ++j){
        const float4 h4 = *(const float4*)&hT[c*25 + j][0];   // 4-addr broadcast
        a00=fmaf(w[j],h4.x,a00); a01=fmaf(w[j],h4.y,a01);
        a02=fmaf(w[j],h4.z,a02); a03=fmaf(w[j],h4.w,a03);
        a10=fmaf(w[25+j],h4.x,a10); a11=fmaf(w[25+j],h4.y,a11);
        a12=fmaf(w[25+j],h4.z,a12); a13=fmaf(w[25+j],h4.w,a13);
      }
      a00=qsum(a00); a01=qsum(a01); a02=qsum(a02); a03=qsum(a03);
      a10=qsum(a10); a11=qsum(a11); a12=qsum(a12); a13=qsum(a13);
      if (c == 0) *(float4*)&G[r0][0] = make_float4(a00,a01,a02,a03);
      if (c == 1) *(float4*)&G[r1][0] = make_float4(a10,a11,a12,a13);
    }
    __syncthreads();
    if (t < 100){
      const float4 gr = *(const float4*)&G[t][0];
      const float4 gz = *(const float4*)&G[t+100][0];
      const float4 gn = *(const float4*)&G[t+200][0];
      const float4 ho = *(const float4*)&hT[t][0];
      const float x0 = xs[0][s], x1v = xs[1][s], x2v = xs[2][s], x3v = xs[3][s];
      float4 hn;
      #define L1GATE(cmp, xv) { \
        const float rr = sigf(fmaf(wr,(xv),br) + gr.cmp + cr); \
        const float zz = sigf(fmaf(wz,(xv),bz) + gz.cmp + cz); \
        const float nn = tanhf_fast(fmaf(wn,(xv),bn) + rr*(gn.cmp + cn)); \
        hn.cmp = nn + zz*(ho.cmp - nn); }
      L1GATE(x, x0) L1GATE(y, x1v) L1GATE(z, x2v) L1GATE(w, x3v)
      #undef L1GATE
      *(float4*)&hT[t][0] = hn;
      if ((s & 3) == 3){
        const int cs = s >> 2;
        *(float4*)(x1 + ((size_t)(cs*256 + blk)*100 + t)*4) = hn;
      }
      if (s == 511){
        out[(size_t)(b0+0)*400 + obase + t] = hn.x;
        out[(size_t)(b0+1)*400 + obase + t] = hn.y;
        out[(size_t)(b0+2)*400 + obase + t] = hn.z;
        out[(size_t)(b0+3)*400 + obase + t] = hn.w;
      }
    }
    __syncthreads();
  }
}

// ---------------------------------------------------------------------------
// L2: I=100, H=50, 128 steps, lane-3 chains only (2048 total), 4 chains/blk.
// Gx (t<300): rows 2p,2p+1 of 150 x-rows, cols c*25..+25 of x (w: 50 VGPR).
// Gh (300<=t<600): rows of 150 h-rows, cols c*13..+13 (pad 52).
// Stagers (600<=t<640): prefetch next x tile into double buffer.
// ---------------------------------------------------------------------------
__global__ __launch_bounds__(640, 5)
void gru_l2(const float* __restrict__ x1f, const float* __restrict__ x1b,
            const float* __restrict__ wih_f, const float* __restrict__ whh_f,
            const float* __restrict__ bih_f, const float* __restrict__ bhh_f,
            const float* __restrict__ wih_b, const float* __restrict__ whh_b,
            const float* __restrict__ bih_b, const float* __restrict__ bhh_b,
            float* __restrict__ x2f, float* __restrict__ x2b,
            float* __restrict__ out)
{
  const int dir = (int)(blockIdx.x >> 8);
  const int blk = (int)(blockIdx.x & 255);
  const int t   = (int)threadIdx.x;
  const float* __restrict__ wih = dir ? wih_b : wih_f;
  const float* __restrict__ whh = dir ? whh_b : whh_f;
  const float* __restrict__ bih = dir ? bih_b : bih_f;
  const float* __restrict__ bhh = dir ? bhh_b : bhh_f;
  const float* __restrict__ x1 = dir ? x1b : x1f;
  float* __restrict__ x2 = dir ? x2b : x2f;
  const int obase = dir ? 300 : 100;
  const int b0 = blk * 4;

  __shared__ __align__(16) float xB[2][100][4];
  __shared__ __align__(16) float hB[52][4];
  __shared__ __align__(16) float Sx[150][4];
  __shared__ __align__(16) float Sh[150][4];

  float w[50];
  if (t < 300){
    const int p = t >> 2, c = t & 3;
    const int r0 = 2*p, r1 = 2*p + 1;
    #pragma unroll
    for (int j = 0; j < 25; ++j){
      w[j]    = wih[r0*100 + c*25 + j];
      w[25+j] = wih[r1*100 + c*25 + j];
    }
  } else if (t < 600){
    const int th = t - 300;
    const int p = th >> 2, c = th & 3;
    const int r0 = 2*p, r1 = 2*p + 1;
    #pragma unroll
    for (int j = 0; j < 13; ++j){
      const int col = c*13 + j;
      w[j]    = (col < 50) ? whh[r0*50 + col] : 0.f;
      w[13+j] = (col < 50) ? whh[r1*50 + col] : 0.f;
    }
  }
  float bcr=0,bcz=0,bn_=0,cn_=0;
  if (t < 50){
    bcr = bih[t] + bhh[t];
    bcz = bih[t+50] + bhh[t+50];
    bn_ = bih[t+100];
    cn_ = bhh[t+100];
  }
  if (t < 52) *(float4*)&hB[t][0] = make_float4(0.f,0.f,0.f,0.f);
  for (int j = t; j < 100; j += 640)
    *(float4*)&xB[0][j][0] = *(const float4*)(x1 + ((size_t)(0*256 + blk)*100 + j)*4);
  __syncthreads();

  #pragma unroll 1
  for (int s = 0; s < 128; ++s){
    if (t < 300){
      const int c = t & 3;
      const int r0 = 2*(t>>2), r1 = r0 + 1;
      float a00=0,a01=0,a02=0,a03=0,a10=0,a11=0,a12=0,a13=0;
      const int buf = s & 1;
      #pragma unroll
      for (int j = 0; j < 25; ++j){
        const float4 v = *(const float4*)&xB[buf][c*25 + j][0];
        a00=fmaf(w[j],v.x,a00); a01=fmaf(w[j],v.y,a01);
        a02=fmaf(w[j],v.z,a02); a03=fmaf(w[j],v.w,a03);
        a10=fmaf(w[25+j],v.x,a10); a11=fmaf(w[25+j],v.y,a11);
        a12=fmaf(w[25+j],v.z,a12); a13=fmaf(w[25+j],v.w,a13);
      }
      a00=qsum(a00); a01=qsum(a01); a02=qsum(a02); a03=qsum(a03);
      a10=qsum(a10); a11=qsum(a11); a12=qsum(a12); a13=qsum(a13);
      if (c == 0) *(float4*)&Sx[r0][0] = make_float4(a00,a01,a02,a03);
      if (c == 1) *(float4*)&Sx[r1][0] = make_float4(a10,a11,a12,a13);
    } else if (t < 600){
      const int th = t - 300;
      const int c = th & 3;
      const int r0 = 2*(th>>2), r1 = r0 + 1;
      float a00=0,a01=0,a02=0,a03=0,a10=0,a11=0,a12=0,a13=0;
      #pragma unroll
      for (int j = 0; j < 13; ++j){
        const float4 v = *(const float4*)&hB[c*13 + j][0];
        a00=fmaf(w[j],v.x,a00); a01=fmaf(w[j],v.y,a01);
        a02=fmaf(w[j],v.z,a02); a03=fmaf(w[j],v.w,a03);
        a10=fmaf(w[13+j],v.x,a10); a11=fmaf(w[13+j],v.y,a11);
        a12=fmaf(w[13+j],v.z,a12); a13=fmaf(w[13+j],v.w,a13);
      }
      a00=qsum(a00); a01=qsum(a01); a02=qsum(a02); a03=qsum(a03);
      a10=qsum(a10); a11=qsum(a11); a12=qsum(a12); a13=qsum(a13);
      if (c == 0) *(float4*)&Sh[r0][0] = make_float4(a00,a01,a02,a03);
      if (c == 1) *(float4*)&Sh[r1][0] = make_float4(a10,a11,a12,a13);
    } else {
      if (s + 1 < 128){
        const int nb = (s + 1) & 1;
        for (int j = t - 600; j < 100; j += 40){
          const float4 v = *(const float4*)(x1 + ((size_t)((s+1)*256 + blk)*100 + j)*4);
          *(float4*)&xB[nb][j][0] = v;
        }
      }
    }
    __syncthreads();
    if (t < 50){
      const float4 sxr = *(const float4*)&Sx[t][0];
      const float4 sxz = *(const float4*)&Sx[t+50][0];
      const float4 sxn = *(const float4*)&Sx[t+100][0];
      const float4 shr = *(const float4*)&Sh[t][0];
      const float4 shz = *(const float4*)&Sh[t+50][0];
      const float4 shn = *(const float4*)&Sh[t+100][0];
      const float4 ho  = *(const float4*)&hB[t][0];
      float4 hn;
      #define LGATE(cmp) { \
        const float rr = sigf(sxr.cmp + shr.cmp + bcr); \
        const float zz = sigf(sxz.cmp + shz.cmp + bcz); \
        const float nn = tanhf_fast(sxn.cmp + bn_ + rr*(shn.cmp + cn_)); \
        hn.cmp = nn + zz*(ho.cmp - nn); }
      LGATE(x) LGATE(y) LGATE(z) LGATE(w)
      #undef LGATE
      *(float4*)&hB[t][0] = hn;
      if ((s & 3) == 3){
        const int k2 = s >> 2;
        *(float4*)(x2 + ((size_t)(k2*256 + blk)*50 + t)*4) = hn;
      }
      if (s == 127){
        out[(size_t)(b0+0)*400 + obase + t] = hn.x;
        out[(size_t)(b0+1)*400 + obase + t] = hn.y;
        out[(size_t)(b0+2)*400 + obase + t] = hn.z;
        out[(size_t)(b0+3)*400 + obase + t] = hn.w;
      }
    }
    __syncthreads();
  }
}

// ---------------------------------------------------------------------------
// L3: I=50, H=50, 32 steps, lane-15 chains only. All x staged upfront (26KB).
// ---------------------------------------------------------------------------
__global__ __launch_bounds__(640, 5)
void gru_l3(const float* __restrict__ x2f, const float* __restrict__ x2b,
            const float* __restrict__ wih_f, const float* __restrict__ whh_f,
            const float* __restrict__ bih_f, const float* __restrict__ bhh_f,
            const float* __restrict__ wih_b, const float* __restrict__ whh_b,
            const float* __restrict__ bih_b, const float* __restrict__ bhh_b,
            float* __restrict__ out)
{
  const int dir = (int)(blockIdx.x >> 8);
  const int blk = (int)(blockIdx.x & 255);
  const int t   = (int)threadIdx.x;
  const float* __restrict__ wih = dir ? wih_b : wih_f;
  const float* __restrict__ whh = dir ? whh_b : whh_f;
  const float* __restrict__ bih = dir ? bih_b : bih_f;
  const float* __restrict__ bhh = dir ? bhh_b : bhh_f;
  const float* __restrict__ x2 = dir ? x2b : x2f;
  const int obase = dir ? 350 : 150;
  const int b0 = blk * 4;

  __shared__ __align__(16) float xall[32][52][4];
  __shared__ __align__(16) float hB[52][4];
  __shared__ __align__(16) float Sx[150][4];
  __shared__ __align__(16) float Sh[150][4];

  float w[26];
  if (t < 300){
    const int p = t >> 2, c = t & 3;
    const int r0 = 2*p, r1 = 2*p + 1;
    #pragma unroll
    for (int j = 0; j < 13; ++j){
      const int col = c*13 + j;
      w[j]    = (col < 50) ? wih[r0*50 + col] : 0.f;
      w[13+j] = (col < 50) ? wih[r1*50 + col] : 0.f;
    }
  } else if (t < 600){
    const int th = t - 300;
    const int p = th >> 2, c = th & 3;
    const int r0 = 2*p, r1 = 2*p + 1;
    #pragma unroll
    for (int j = 0; j < 13; ++j){
      const int col = c*13 + j;
      w[j]    = (col < 50) ? whh[r0*50 + col] : 0.f;
      w[13+j] = (col < 50) ? whh[r1*50 + col] : 0.f;
    }
  }
  float bcr=0,bcz=0,bn_=0,cn_=0;
  if (t < 50){
    bcr = bih[t] + bhh[t];
    bcz = bih[t+50] + bhh[t+50];
    bn_ = bih[t+100];
    cn_ = bhh[t+100];
  }
  if (t < 52) *(float4*)&hB[t][0] = make_float4(0.f,0.f,0.f,0.f);
  if (t < 64) *(float4*)&xall[t>>1][50 + (t&1)][0] = make_float4(0.f,0.f,0.f,0.f);
  for (int i = t; i < 1600; i += 640){
    const int k2 = i / 50, j = i - k2*50;
    *(float4*)&xall[k2][j][0] = *(const float4*)(x2 + ((size_t)(k2*256 + blk)*50 + j)*4);
  }
  __syncthreads();

  #pragma unroll 1
  for (int s = 0; s < 32; ++s){
    if (t < 300){
      const int c = t & 3;
      const int r0 = 2*(t>>2), r1 = r0 + 1;
      float a00=0,a01=0,a02=0,a03=0,a10=0,a11=0,a12=0,a13=0;
      #pragma unroll
      for (int j = 0; j < 13; ++j){
        const float4 v = *(const float4*)&xall[s][c*13 + j][0];
        a00=fmaf(w[j],v.x,a00); a01=fmaf(w[j],v.y,a01);
        a02=fmaf(w[j],v.z,a02); a03=fmaf(w[j],v.w,a03);
        a10=fmaf(w[13+j],v.x,a10); a11=fmaf(w[13+j],v.y,a11);
        a12=fmaf(w[13+j],v.z,a12); a13=fmaf(w[13+j],v.w,a13);
      }
      a00=qsum(a00); a01=qsum(a01); a02=qsum(a02); a03=qsum(a03);
      a10=qsum(a10); a11=qsum(a11); a12=qsum(a12); a13=qsum(a13);
      if (c == 0) *(float4*)&Sx[r0][0] = make_float4(a00,a01,a02,a03);
      if (c == 1) *(float4*)&Sx[r1][0] = make_float4(a10,a11,a12,a13);
    } else if (t < 600){
      const int th = t - 300;
      const int c = th & 3;
      const int r0 = 2*(th>>2), r1 = r0 + 1;
      float a00=0,a01=0,a02=0,a03=0,a10=0,a11=0,a12=0,a13=0;
      #pragma unroll
      for (int j = 0; j < 13; ++j){
        const float4 v = *(const float4*)&hB[c*13 + j][0];
        a00=fmaf(w[j],v.x,a00); a01=fmaf(w[j],v.y,a01);
        a02=fmaf(w[j],v.z,a02); a03=fmaf(w[j],v.w,a03);
        a10=fmaf(w[13+j],v.x,a10); a11=fmaf(w[13+j],v.y,a11);
        a12=fmaf(w[13+j],v.z,a12); a13=fmaf(w[13+j],v.w,a13);
      }
      a00=qsum(a00); a01=qsum(a01); a02=qsum(a02); a03=qsum(a03);
      a10=qsum(a10); a11=qsum(a11); a12=qsum(a12); a13=qsum(a13);
      if (c == 0) *(float4*)&Sh[r0][0] = make_float4(a00,a01,a02,a03);
      if (c == 1) *(float4*)&Sh[r1][0] = make_float4(a10,a11,a12,a13);
    }
    __syncthreads();
    if (t < 50){
      const float4 sxr = *(const float4*)&Sx[t][0];
      const float4 sxz = *(const float4*)&Sx[t+50][0];
      const float4 sxn = *(const float4*)&Sx[t+100][0];
      const float4 shr = *(const float4*)&Sh[t][0];
      const float4 shz = *(const float4*)&Sh[t+50][0];
      const float4 shn = *(const float4*)&Sh[t+100][0];
      const float4 ho  = *(const float4*)&hB[t][0];
      float4 hn;
      #define LGATE(cmp) { \
        const float rr = sigf(sxr.cmp + shr.cmp + bcr); \
        const float zz = sigf(sxz.cmp + shz.cmp + bcz); \
        const float nn = tanhf_fast(sxn.cmp + bn_ + rr*(shn.cmp + cn_)); \
        hn.cmp = nn + zz*(ho.cmp - nn); }
      LGATE(x) LGATE(y) LGATE(z) LGATE(w)
      #undef LGATE
      *(float4*)&hB[t][0] = hn;
      if (s == 31){
        out[(size_t)(b0+0)*400 + obase + t] = hn.x;
        out[(size_t)(b0+1)*400 + obase + t] = hn.y;
        out[(size_t)(b0+2)*400 + obase + t] = hn.z;
        out[(size_t)(b0+3)*400 + obase + t] = hn.w;
      }
    }
    __syncthreads();
  }
}

extern "C" void kernel_launch(void* const* d_in, const int* in_sizes, int n_in,
                              void* d_out, int out_size, void* d_ws, size_t ws_size,
                              hipStream_t stream)
{
  const float* data   = (const float*)d_in[0];
  const float* f1_wih = (const float*)d_in[1];
  const float* f1_whh = (const float*)d_in[2];
  const float* f1_bih = (const float*)d_in[3];
  const float* f1_bhh = (const float*)d_in[4];
  const float* f2_wih = (const float*)d_in[5];
  const float* f2_whh = (const float*)d_in[6];
  const float* f2_bih = (const float*)d_in[7];
  const float* f2_bhh = (const float*)d_in[8];
  const float* f3_wih = (const float*)d_in[9];
  const float* f3_whh = (const float*)d_in[10];
  const float* f3_bih = (const float*)d_in[11];
  const float* f3_bhh = (const float*)d_in[12];
  const float* b1_wih = (const float*)d_in[13];
  const float* b1_whh = (const float*)d_in[14];
  const float* b1_bih = (const float*)d_in[15];
  const float* b1_bhh = (const float*)d_in[16];
  const float* b2_wih = (const float*)d_in[17];
  const float* b2_whh = (const float*)d_in[18];
  const float* b2_bih = (const float*)d_in[19];
  const float* b2_bhh = (const float*)d_in[20];
  const float* b3_wih = (const float*)d_in[21];
  const float* b3_whh = (const float*)d_in[22];
  const float* b3_bih = (const float*)d_in[23];
  const float* b3_bhh = (const float*)d_in[24];
  float* out = (float*)d_out;

  const size_t X1N = (size_t)128 * 256 * 100 * 4;  // [cs][blk][j][4]
  const size_t X2N = (size_t)32 * 256 * 50 * 4;    // [k2][blk][j][4]
  if (ws_size < (2 * X1N + 2 * X2N) * sizeof(float)) return;
  float* wsf = (float*)d_ws;
  float* x1f = wsf;
  float* x1b = wsf + X1N;
  float* x2f = wsf + 2 * X1N;
  float* x2b = wsf + 2 * X1N + X2N;

  gru_l1<<<dim3(512), dim3(640), 0, stream>>>(
      data, f1_wih, f1_whh, f1_bih, f1_bhh,
      b1_wih, b1_whh, b1_bih, b1_bhh, x1f, x1b, out);
  gru_l2<<<dim3(512), dim3(640), 0, stream>>>(
      x1f, x1b, f2_wih, f2_whh, f2_bih, f2_bhh,
      b2_wih, b2_whh, b2_bih, b2_bhh, x2f, x2b, out);
  gru_l3<<<dim3(512), dim3(640), 0, stream>>>(
      x2f, x2b, f3_wih, f3_whh, f3_bih, f3_bhh,
      b3_wih, b3_whh, b3_bih, b3_bhh, out);
}

// Round 4
// 1440.103 us; speedup vs baseline: 6.6544x; 6.6544x over previous
//
#include <hip/hip_runtime.h>
#include <math.h>

static __device__ __forceinline__ float sigf(float x){ return 1.0f/(1.0f+__expf(-x)); }
static __device__ __forceinline__ float tanhf_fast(float x){
  float ax=fabsf(x); float e=__expf(-2.0f*ax); float t=(1.0f-e)/(1.0f+e); return copysignf(t,x);
}
// sum across quad (lanes 4k..4k+3); result valid in all 4 lanes (quad_perm is explicit)
static __device__ __forceinline__ float qsum(float v){
  v += __int_as_float(__builtin_amdgcn_mov_dpp(__float_as_int(v),0xB1,0xF,0xF,true)); // quad_perm xor1
  v += __int_as_float(__builtin_amdgcn_mov_dpp(__float_as_int(v),0x4E,0xF,0xF,true)); // quad_perm xor2
  return v;
}
// add value of lane^4 via ds_swizzle xor-mode (0x101F = xor 4, and 0x1F):
// direction-unambiguous; after qsum this gives the full 8-lane octet sum in ALL 8 lanes.
static __device__ __forceinline__ float rsum4(float v){
  return v + __int_as_float(__builtin_amdgcn_ds_swizzle(__float_as_int(v), 0x101F));
}
static __device__ __forceinline__ float sel4(int c, float4 v){
  float r=v.x; r=(c==1)?v.y:r; r=(c==2)?v.z:r; r=(c==3)?v.w:r; return r;
}

#define LDROW(P, V0,V1,V2,V3,V4,V5,VS) \
  V0 = make_float4((P)[0],(P)[1],(P)[2],(P)[3]); \
  V1 = make_float4((P)[4],(P)[5],(P)[6],(P)[7]); \
  V2 = make_float4((P)[8],(P)[9],(P)[10],(P)[11]); \
  V3 = make_float4((P)[12],(P)[13],(P)[14],(P)[15]); \
  V4 = make_float4((P)[16],(P)[17],(P)[18],(P)[19]); \
  V5 = make_float4((P)[20],(P)[21],(P)[22],(P)[23]); \
  VS = (P)[24];

// ---------------------------------------------------------------------------
// L1: I=1, H=100, 512 steps, 4 chains/block, 512 blocks (256 fwd + 256 bwd).
// 400 workers = 100 quads; quad owns unit u (rows u,u+100,u+200), lane c owns
// cols c*25..+25 (weights in NAMED float4s -> cannot spill). qsum gives each
// lane full gate sums; lane c finalizes chain c. 1 barrier/step, hT dbuf.
// ---------------------------------------------------------------------------
__global__ __launch_bounds__(512, 4)
void gru_l1(const float* __restrict__ data,
            const float* __restrict__ wih_f, const float* __restrict__ whh_f,
            const float* __restrict__ bih_f, const float* __restrict__ bhh_f,
            const float* __restrict__ wih_b, const float* __restrict__ whh_b,
            const float* __restrict__ bih_b, const float* __restrict__ bhh_b,
            float* __restrict__ x1f, float* __restrict__ x1b,
            float* __restrict__ out)
{
  const int dir = (int)(blockIdx.x >> 8);
  const int blk = (int)(blockIdx.x & 255);
  const int t   = (int)threadIdx.x;
  const float* __restrict__ wih = dir ? wih_b : wih_f;
  const float* __restrict__ whh = dir ? whh_b : whh_f;
  const float* __restrict__ bih = dir ? bih_b : bih_f;
  const float* __restrict__ bhh = dir ? bhh_b : bhh_f;
  float* __restrict__ x1 = dir ? x1b : x1f;
  const int obase = dir ? 200 : 0;
  const int b0 = blk * 4;

  __shared__ __align__(16) float xs[512][4];
  __shared__ __align__(16) float hT[2][100][4];

  { const int sidx = dir ? (511 - t) : t;
    xs[t][0] = data[(size_t)(b0+0)*512 + sidx];
    xs[t][1] = data[(size_t)(b0+1)*512 + sidx];
    xs[t][2] = data[(size_t)(b0+2)*512 + sidx];
    xs[t][3] = data[(size_t)(b0+3)*512 + sidx]; }
  if (t < 100) *(float4*)&hT[0][t][0] = make_float4(0.f,0.f,0.f,0.f);

  const int uu = t >> 2;
  const int u  = (uu > 99) ? 99 : uu;   // clamp so loads are unconditional
  const int c  = t & 3;
  const float* pr = whh + (size_t)(u      )*100 + c*25;
  const float* pz = whh + (size_t)(u + 100)*100 + c*25;
  const float* pn = whh + (size_t)(u + 200)*100 + c*25;
  float4 R0,R1,R2,R3,R4,R5; float R6;
  float4 Z0,Z1,Z2,Z3,Z4,Z5; float Z6;
  float4 N0,N1,N2,N3,N4,N5; float N6;
  LDROW(pr, R0,R1,R2,R3,R4,R5,R6)
  LDROW(pz, Z0,Z1,Z2,Z3,Z4,Z5,Z6)
  LDROW(pn, N0,N1,N2,N3,N4,N5,N6)
  const float wxr = wih[u], wxz = wih[u+100], wxn = wih[u+200];
  const float bxr = bih[u], bxz = bih[u+100], bxn = bih[u+200];
  const float bhr = bhh[u], bhz = bhh[u+100], bhn = bhh[u+200];
  __syncthreads();

  #pragma unroll 1
  for (int s = 0; s < 512; ++s){
    const int cur = s & 1, nxt = cur ^ 1;
    if (t < 400){
      const float* hb = &hT[cur][c*25][0];
      float ar0=0,ar1=0,ar2=0,ar3=0, az0=0,az1=0,az2=0,az3=0, an0=0,an1=0,an2=0,an3=0;
      #define L1C(J, WR, WZ, WN) { const float4 h4 = *(const float4*)(hb + 4*(J)); \
        ar0=fmaf(WR,h4.x,ar0); ar1=fmaf(WR,h4.y,ar1); ar2=fmaf(WR,h4.z,ar2); ar3=fmaf(WR,h4.w,ar3); \
        az0=fmaf(WZ,h4.x,az0); az1=fmaf(WZ,h4.y,az1); az2=fmaf(WZ,h4.z,az2); az3=fmaf(WZ,h4.w,az3); \
        an0=fmaf(WN,h4.x,an0); an1=fmaf(WN,h4.y,an1); an2=fmaf(WN,h4.z,an2); an3=fmaf(WN,h4.w,an3); }
      L1C(0 ,R0.x,Z0.x,N0.x) L1C(1 ,R0.y,Z0.y,N0.y) L1C(2 ,R0.z,Z0.z,N0.z) L1C(3 ,R0.w,Z0.w,N0.w)
      L1C(4 ,R1.x,Z1.x,N1.x) L1C(5 ,R1.y,Z1.y,N1.y) L1C(6 ,R1.z,Z1.z,N1.z) L1C(7 ,R1.w,Z1.w,N1.w)
      L1C(8 ,R2.x,Z2.x,N2.x) L1C(9 ,R2.y,Z2.y,N2.y) L1C(10,R2.z,Z2.z,N2.z) L1C(11,R2.w,Z2.w,N2.w)
      L1C(12,R3.x,Z3.x,N3.x) L1C(13,R3.y,Z3.y,N3.y) L1C(14,R3.z,Z3.z,N3.z) L1C(15,R3.w,Z3.w,N3.w)
      L1C(16,R4.x,Z4.x,N4.x) L1C(17,R4.y,Z4.y,N4.y) L1C(18,R4.z,Z4.z,N4.z) L1C(19,R4.w,Z4.w,N4.w)
      L1C(20,R5.x,Z5.x,N5.x) L1C(21,R5.y,Z5.y,N5.y) L1C(22,R5.z,Z5.z,N5.z) L1C(23,R5.w,Z5.w,N5.w)
      L1C(24,R6  ,Z6  ,N6  )
      #undef L1C
      ar0=qsum(ar0); ar1=qsum(ar1); ar2=qsum(ar2); ar3=qsum(ar3);
      az0=qsum(az0); az1=qsum(az1); az2=qsum(az2); az3=qsum(az3);
      an0=qsum(an0); an1=qsum(an1); an2=qsum(an2); an3=qsum(an3);
      const float Ar = sel4(c, make_float4(ar0,ar1,ar2,ar3));
      const float Az = sel4(c, make_float4(az0,az1,az2,az3));
      const float An = sel4(c, make_float4(an0,an1,an2,an3));
      const float ho = sel4(c, *(const float4*)&hT[cur][u][0]);
      const float xc = sel4(c, *(const float4*)&xs[s][0]);
      const float r = sigf(fmaf(wxr, xc, bxr) + Ar + bhr);
      const float z = sigf(fmaf(wxz, xc, bxz) + Az + bhz);
      const float n = tanhf_fast(fmaf(wxn, xc, bxn) + r*(An + bhn));
      const float hnew = n + z*(ho - n);
      hT[nxt][u][c] = hnew;
      if ((s & 3) == 3) x1[(((size_t)(s>>2)*256 + blk)*100 + u)*4 + c] = hnew;
      if (s == 511)     out[(size_t)(b0 + c)*400 + obase + u] = hnew;
    }
    __syncthreads();
  }
}

// ---------------------------------------------------------------------------
// L2: I=100, H=50, 128 steps, lane-3 chains, 4 chains/block, 512 blocks.
// Combined [x;h] buffer xh[2][152][4] (rows 0-99 x, 100-149 h, 150-151 pad).
// 400 workers = 50 octets; lane l owns 19 combined cols; 4 weights/col
// (wr,wz,wnx,wnh — n-gate split via zero-padding). qsum + xor-4 swizzle reduce.
// Stagers t in [400,500) double-buffer next step's x. 1 barrier/step.
// ---------------------------------------------------------------------------
__global__ __launch_bounds__(512, 4)
void gru_l2(const float* __restrict__ x1f, const float* __restrict__ x1b,
            const float* __restrict__ wih_f, const float* __restrict__ whh_f,
            const float* __restrict__ bih_f, const float* __restrict__ bhh_f,
            const float* __restrict__ wih_b, const float* __restrict__ whh_b,
            const float* __restrict__ bih_b, const float* __restrict__ bhh_b,
            float* __restrict__ x2f, float* __restrict__ x2b,
            float* __restrict__ out)
{
  const int dir = (int)(blockIdx.x >> 8);
  const int blk = (int)(blockIdx.x & 255);
  const int t   = (int)threadIdx.x;
  const float* __restrict__ wih = dir ? wih_b : wih_f;
  const float* __restrict__ whh = dir ? whh_b : whh_f;
  const float* __restrict__ bih = dir ? bih_b : bih_f;
  const float* __restrict__ bhh = dir ? bhh_b : bhh_f;
  const float* __restrict__ x1 = dir ? x1b : x1f;
  float* __restrict__ x2 = dir ? x2b : x2f;
  const int obase = dir ? 300 : 100;
  const int b0 = blk * 4;

  __shared__ __align__(16) float xh[2][152][4];

  const int oct = t >> 3;
  const int u   = (oct > 49) ? 49 : oct;
  const int l   = t & 7;
  const int cb  = 19 * l;           // combined col base (0..133)
  float4 W0,W1,W2,W3,W4,W5,W6,W7,W8,W9,W10,W11,W12,W13,W14,W15,W16,W17,W18;
  #define L2LW(J, V) { const int g = cb + (J); \
    const float wr_ = (g<100) ? wih[(size_t)(u     )*100+g] : ((g<150)? whh[(size_t)(u     )*50+g-100] : 0.f); \
    const float wz_ = (g<100) ? wih[(size_t)(u + 50)*100+g] : ((g<150)? whh[(size_t)(u + 50)*50+g-100] : 0.f); \
    const float wx_ = (g<100) ? wih[(size_t)(u +100)*100+g] : 0.f; \
    const float wh_ = (g>=100 && g<150) ? whh[(size_t)(u +100)*50+g-100] : 0.f; \
    V = make_float4(wr_, wz_, wx_, wh_); }
  L2LW(0,W0)  L2LW(1,W1)  L2LW(2,W2)  L2LW(3,W3)  L2LW(4,W4)  L2LW(5,W5)  L2LW(6,W6)
  L2LW(7,W7)  L2LW(8,W8)  L2LW(9,W9)  L2LW(10,W10) L2LW(11,W11) L2LW(12,W12) L2LW(13,W13)
  L2LW(14,W14) L2LW(15,W15) L2LW(16,W16) L2LW(17,W17) L2LW(18,W18)
  #undef L2LW
  const float bcr = bih[u] + bhh[u];
  const float bcz = bih[u+50] + bhh[u+50];
  const float bxn = bih[u+100];
  const float bhn = bhh[u+100];

  for (int i = t; i < 104; i += 512){            // zero h rows + pads, both buffers
    const int bi = (i >= 52) ? 1 : 0;
    const int row = 100 + (i - bi*52);
    *(float4*)&xh[bi][row][0] = make_float4(0.f,0.f,0.f,0.f);
  }
  if (t < 100)                                    // stage x for step 0
    *(float4*)&xh[0][t][0] = *(const float4*)(x1 + (((size_t)0*256 + blk)*100 + t)*4);
  __syncthreads();

  #pragma unroll 1
  for (int s = 0; s < 128; ++s){
    const int cur = s & 1, nxt = cur ^ 1;
    if (t < 400){
      const float* hb = &xh[cur][cb][0];
      float ar0=0,ar1=0,ar2=0,ar3=0, az0=0,az1=0,az2=0,az3=0;
      float ax0=0,ax1=0,ax2=0,ax3=0, ah0=0,ah1=0,ah2=0,ah3=0;
      #define L2C(J, WV) { const float4 h4 = *(const float4*)(hb + 4*(J)); \
        ar0=fmaf(WV.x,h4.x,ar0); ar1=fmaf(WV.x,h4.y,ar1); ar2=fmaf(WV.x,h4.z,ar2); ar3=fmaf(WV.x,h4.w,ar3); \
        az0=fmaf(WV.y,h4.x,az0); az1=fmaf(WV.y,h4.y,az1); az2=fmaf(WV.y,h4.z,az2); az3=fmaf(WV.y,h4.w,az3); \
        ax0=fmaf(WV.z,h4.x,ax0); ax1=fmaf(WV.z,h4.y,ax1); ax2=fmaf(WV.z,h4.z,ax2); ax3=fmaf(WV.z,h4.w,ax3); \
        ah0=fmaf(WV.w,h4.x,ah0); ah1=fmaf(WV.w,h4.y,ah1); ah2=fmaf(WV.w,h4.z,ah2); ah3=fmaf(WV.w,h4.w,ah3); }
      L2C(0,W0)  L2C(1,W1)  L2C(2,W2)  L2C(3,W3)  L2C(4,W4)  L2C(5,W5)  L2C(6,W6)
      L2C(7,W7)  L2C(8,W8)  L2C(9,W9)  L2C(10,W10) L2C(11,W11) L2C(12,W12) L2C(13,W13)
      L2C(14,W14) L2C(15,W15) L2C(16,W16) L2C(17,W17) L2C(18,W18)
      #undef L2C
      ar0=qsum(ar0); ar1=qsum(ar1); ar2=qsum(ar2); ar3=qsum(ar3);
      az0=qsum(az0); az1=qsum(az1); az2=qsum(az2); az3=qsum(az3);
      ax0=qsum(ax0); ax1=qsum(ax1); ax2=qsum(ax2); ax3=qsum(ax3);
      ah0=qsum(ah0); ah1=qsum(ah1); ah2=qsum(ah2); ah3=qsum(ah3);
      ar0=rsum4(ar0); ar1=rsum4(ar1); ar2=rsum4(ar2); ar3=rsum4(ar3);
      az0=rsum4(az0); az1=rsum4(az1); az2=rsum4(az2); az3=rsum4(az3);
      ax0=rsum4(ax0); ax1=rsum4(ax1); ax2=rsum4(ax2); ax3=rsum4(ax3);
      ah0=rsum4(ah0); ah1=rsum4(ah1); ah2=rsum4(ah2); ah3=rsum4(ah3);
      if (l < 4){
        const float Ar = sel4(l, make_float4(ar0,ar1,ar2,ar3));
        const float Az = sel4(l, make_float4(az0,az1,az2,az3));
        const float Ax = sel4(l, make_float4(ax0,ax1,ax2,ax3));
        const float Ah = sel4(l, make_float4(ah0,ah1,ah2,ah3));
        const float ho = xh[cur][100+u][l];
        const float r = sigf(Ar + bcr);
        const float z = sigf(Az + bcz);
        const float n = tanhf_fast(Ax + bxn + r*(Ah + bhn));
        const float hnew = n + z*(ho - n);
        xh[nxt][100+u][l] = hnew;
        if ((s & 3) == 3) x2[(((size_t)(s>>2)*256 + blk)*50 + u)*4 + l] = hnew;
        if (s == 127)     out[(size_t)(b0 + l)*400 + obase + u] = hnew;
      }
    } else if (t < 500){
      if (s + 1 < 128){
        const int j = t - 400;
        *(float4*)&xh[nxt][j][0] = *(const float4*)(x1 + (((size_t)(s+1)*256 + blk)*100 + j)*4);
      }
    }
    __syncthreads();
  }
}

// ---------------------------------------------------------------------------
// L3: I=50, H=50, 32 steps, lane-15 chains. Same template as L2:
// combined cols 100 (x 0-49, h 50-99, pad 100-103), lane owns 13 cols.
// ---------------------------------------------------------------------------
__global__ __launch_bounds__(512, 4)
void gru_l3(const float* __restrict__ x2f, const float* __restrict__ x2b,
            const float* __restrict__ wih_f, const float* __restrict__ whh_f,
            const float* __restrict__ bih_f, const float* __restrict__ bhh_f,
            const float* __restrict__ wih_b, const float* __restrict__ whh_b,
            const float* __restrict__ bih_b, const float* __restrict__ bhh_b,
            float* __restrict__ out)
{
  const int dir = (int)(blockIdx.x >> 8);
  const int blk = (int)(blockIdx.x & 255);
  const int t   = (int)threadIdx.x;
  const float* __restrict__ wih = dir ? wih_b : wih_f;
  const float* __restrict__ whh = dir ? whh_b : whh_f;
  const float* __restrict__ bih = dir ? bih_b : bih_f;
  const float* __restrict__ bhh = dir ? bhh_b : bhh_f;
  const float* __restrict__ x2 = dir ? x2b : x2f;
  const int obase = dir ? 350 : 150;
  const int b0 = blk * 4;

  __shared__ __align__(16) float xh[2][104][4];

  const int oct = t >> 3;
  const int u   = (oct > 49) ? 49 : oct;
  const int l   = t & 7;
  const int cb  = 13 * l;           // 0..91
  float4 W0,W1,W2,W3,W4,W5,W6,W7,W8,W9,W10,W11,W12;
  #define L3LW(J, V) { const int g = cb + (J); \
    const float wr_ = (g<50) ? wih[(size_t)(u     )*50+g] : ((g<100)? whh[(size_t)(u     )*50+g-50] : 0.f); \
    const float wz_ = (g<50) ? wih[(size_t)(u + 50)*50+g] : ((g<100)? whh[(size_t)(u + 50)*50+g-50] : 0.f); \
    const float wx_ = (g<50) ? wih[(size_t)(u +100)*50+g] : 0.f; \
    const float wh_ = (g>=50 && g<100) ? whh[(size_t)(u +100)*50+g-50] : 0.f; \
    V = make_float4(wr_, wz_, wx_, wh_); }
  L3LW(0,W0) L3LW(1,W1) L3LW(2,W2) L3LW(3,W3) L3LW(4,W4) L3LW(5,W5) L3LW(6,W6)
  L3LW(7,W7) L3LW(8,W8) L3LW(9,W9) L3LW(10,W10) L3LW(11,W11) L3LW(12,W12)
  #undef L3LW
  const float bcr = bih[u] + bhh[u];
  const float bcz = bih[u+50] + bhh[u+50];
  const float bxn = bih[u+100];
  const float bhn = bhh[u+100];

  for (int i = t; i < 108; i += 512){            // zero h rows + pads, both buffers
    const int bi = (i >= 54) ? 1 : 0;
    const int row = 50 + (i - bi*54);
    *(float4*)&xh[bi][row][0] = make_float4(0.f,0.f,0.f,0.f);
  }
  if (t < 50)
    *(float4*)&xh[0][t][0] = *(const float4*)(x2 + (((size_t)0*256 + blk)*50 + t)*4);
  __syncthreads();

  #pragma unroll 1
  for (int s = 0; s < 32; ++s){
    const int cur = s & 1, nxt = cur ^ 1;
    if (t < 400){
      const float* hb = &xh[cur][cb][0];
      float ar0=0,ar1=0,ar2=0,ar3=0, az0=0,az1=0,az2=0,az3=0;
      float ax0=0,ax1=0,ax2=0,ax3=0, ah0=0,ah1=0,ah2=0,ah3=0;
      #define L3C(J, WV) { const float4 h4 = *(const float4*)(hb + 4*(J)); \
        ar0=fmaf(WV.x,h4.x,ar0); ar1=fmaf(WV.x,h4.y,ar1); ar2=fmaf(WV.x,h4.z,ar2); ar3=fmaf(WV.x,h4.w,ar3); \
        az0=fmaf(WV.y,h4.x,az0); az1=fmaf(WV.y,h4.y,az1); az2=fmaf(WV.y,h4.z,az2); az3=fmaf(WV.y,h4.w,az3); \
        ax0=fmaf(WV.z,h4.x,ax0); ax1=fmaf(WV.z,h4.y,ax1); ax2=fmaf(WV.z,h4.z,ax2); ax3=fmaf(WV.z,h4.w,ax3); \
        ah0=fmaf(WV.w,h4.x,ah0); ah1=fmaf(WV.w,h4.y,ah1); ah2=fmaf(WV.w,h4.z,ah2); ah3=fmaf(WV.w,h4.w,ah3); }
      L3C(0,W0) L3C(1,W1) L3C(2,W2) L3C(3,W3) L3C(4,W4) L3C(5,W5) L3C(6,W6)
      L3C(7,W7) L3C(8,W8) L3C(9,W9) L3C(10,W10) L3C(11,W11) L3C(12,W12)
      #undef L3C
      ar0=qsum(ar0); ar1=qsum(ar1); ar2=qsum(ar2); ar3=qsum(ar3);
      az0=qsum(az0); az1=qsum(az1); az2=qsum(az2); az3=qsum(az3);
      ax0=qsum(ax0); ax1=qsum(ax1); ax2=qsum(ax2); ax3=qsum(ax3);
      ah0=qsum(ah0); ah1=qsum(ah1); ah2=qsum(ah2); ah3=qsum(ah3);
      ar0=rsum4(ar0); ar1=rsum4(ar1); ar2=rsum4(ar2); ar3=rsum4(ar3);
      az0=rsum4(az0); az1=rsum4(az1); az2=rsum4(az2); az3=rsum4(az3);
      ax0=rsum4(ax0); ax1=rsum4(ax1); ax2=rsum4(ax2); ax3=rsum4(ax3);
      ah0=rsum4(ah0); ah1=rsum4(ah1); ah2=rsum4(ah2); ah3=rsum4(ah3);
      if (l < 4){
        const float Ar = sel4(l, make_float4(ar0,ar1,ar2,ar3));
        const float Az = sel4(l, make_float4(az0,az1,az2,az3));
        const float Ax = sel4(l, make_float4(ax0,ax1,ax2,ax3));
        const float Ah = sel4(l, make_float4(ah0,ah1,ah2,ah3));
        const float ho = xh[cur][50+u][l];
        const float r = sigf(Ar + bcr);
        const float z = sigf(Az + bcz);
        const float n = tanhf_fast(Ax + bxn + r*(Ah + bhn));
        const float hnew = n + z*(ho - n);
        xh[nxt][50+u][l] = hnew;
        if (s == 31) out[(size_t)(b0 + l)*400 + obase + u] = hnew;
      }
    } else if (t < 450){
      if (s + 1 < 32){
        const int j = t - 400;
        *(float4*)&xh[nxt][j][0] = *(const float4*)(x2 + (((size_t)(s+1)*256 + blk)*50 + j)*4);
      }
    }
    __syncthreads();
  }
}

extern "C" void kernel_launch(void* const* d_in, const int* in_sizes, int n_in,
                              void* d_out, int out_size, void* d_ws, size_t ws_size,
                              hipStream_t stream)
{
  const float* data   = (const float*)d_in[0];
  const float* f1_wih = (const float*)d_in[1];
  const float* f1_whh = (const float*)d_in[2];
  const float* f1_bih = (const float*)d_in[3];
  const float* f1_bhh = (const float*)d_in[4];
  const float* f2_wih = (const float*)d_in[5];
  const float* f2_whh = (const float*)d_in[6];
  const float* f2_bih = (const float*)d_in[7];
  const float* f2_bhh = (const float*)d_in[8];
  const float* f3_wih = (const float*)d_in[9];
  const float* f3_whh = (const float*)d_in[10];
  const float* f3_bih = (const float*)d_in[11];
  const float* f3_bhh = (const float*)d_in[12];
  const float* b1_wih = (const float*)d_in[13];
  const float* b1_whh = (const float*)d_in[14];
  const float* b1_bih = (const float*)d_in[15];
  const float* b1_bhh = (const float*)d_in[16];
  const float* b2_wih = (const float*)d_in[17];
  const float* b2_whh = (const float*)d_in[18];
  const float* b2_bih = (const float*)d_in[19];
  const float* b2_bhh = (const float*)d_in[20];
  const float* b3_wih = (const float*)d_in[21];
  const float* b3_whh = (const float*)d_in[22];
  const float* b3_bih = (const float*)d_in[23];
  const float* b3_bhh = (const float*)d_in[24];
  float* out = (float*)d_out;

  const size_t X1N = (size_t)128 * 256 * 100 * 4;  // [cs][blk][unit][chain]
  const size_t X2N = (size_t)32 * 256 * 50 * 4;    // [k2][blk][unit][chain]
  if (ws_size < (2 * X1N + 2 * X2N) * sizeof(float)) return;
  float* wsf = (float*)d_ws;
  float* x1f = wsf;
  float* x1b = wsf + X1N;
  float* x2f = wsf + 2 * X1N;
  float* x2b = wsf + 2 * X1N + X2N;

  gru_l1<<<dim3(512), dim3(512), 0, stream>>>(
      data, f1_wih, f1_whh, f1_bih, f1_bhh,
      b1_wih, b1_whh, b1_bih, b1_bhh, x1f, x1b, out);
  gru_l2<<<dim3(512), dim3(512), 0, stream>>>(
      x1f, x1b, f2_wih, f2_whh, f2_bih, f2_bhh,
      b2_wih, b2_whh, b2_bih, b2_bhh, x2f, x2b, out);
  gru_l3<<<dim3(512), dim3(512), 0, stream>>>(
      x2f, x2b, f3_wih, f3_whh, f3_bih, f3_bhh,
      b3_wih, b3_whh, b3_bih, b3_bhh, out);
}